// Round 3
// baseline (282.458 us; speedup 1.0000x reference)
//
#include <hip/hip_runtime.h>

// q,k,v: [B=8, d=768, N=6144] fp32; head_dim=32, kernel_size=3
// h = 24 heads, g = 2048 windows; window elem j of window G at n = j*2048 + G
// out flat: [b][gg][hh][kq][dd] contiguous [8, 2048, 24, 3, 32]
//
// Each thread handles 4 consecutive windows (one window-quad g4): all global
// reads become float4 (16B/lane -> 1KB/wave-instruction). PV loops w-outer so
// each window's 384B output chunk is written in 24 tight float4 stores
// (3 open 64B lines/thread -> fits L2, no partial-line eviction/write-amp).
constexpr int CB = 8;
constexpr int CD = 768;
constexpr int CN = 6144;
constexpr int HD = 32;
constexpr int KS = 3;
constexpr int CH = CD / HD;   // 24
constexpr int CG = CN / KS;   // 2048
constexpr int NG4 = CG / 4;   // 512 window-quads
constexpr int CN4 = CN / 4;   // 1536 float4 per row
constexpr int CG4 = CG / 4;   // 512 float4 per j-segment

__device__ __forceinline__ float c4(const float4& f, int w) {
  switch (w) { case 0: return f.x; case 1: return f.y; case 2: return f.z; default: return f.w; }
}

__global__ __launch_bounds__(64) void dilate_attn_kernel(
    const float* __restrict__ q, const float* __restrict__ k,
    const float* __restrict__ v, float* __restrict__ out) {
  const int tid = blockIdx.x * 64 + threadIdx.x;
  const int g4 = tid & (NG4 - 1);       // window-quad, fastest -> wave reads 1KB contiguous
  const int bh = tid >> 9;              // b*24 + hh
  const int hh = bh % CH;
  const int b  = bh / CH;

  const size_t inbase = ((size_t)b * CD + (size_t)hh * HD) * (size_t)CN + (size_t)g4 * 4;
  const float4* qb = reinterpret_cast<const float4*>(q + inbase);
  const float4* kb = reinterpret_cast<const float4*>(k + inbase);
  const float4* vb = reinterpret_cast<const float4*>(v + inbase);

  // ---- scores s[w][kq][kj]
  float s[4][3][3];
  #pragma unroll
  for (int w = 0; w < 4; ++w)
    #pragma unroll
    for (int a = 0; a < 3; ++a)
      #pragma unroll
      for (int c = 0; c < 3; ++c) s[w][a][c] = 0.f;

  #pragma unroll 4
  for (int dd = 0; dd < HD; ++dd) {
    const float4 q0 = qb[dd * CN4 + 0 * CG4];
    const float4 q1 = qb[dd * CN4 + 1 * CG4];
    const float4 q2 = qb[dd * CN4 + 2 * CG4];
    const float4 k0 = kb[dd * CN4 + 0 * CG4];
    const float4 k1 = kb[dd * CN4 + 1 * CG4];
    const float4 k2 = kb[dd * CN4 + 2 * CG4];
    #pragma unroll
    for (int w = 0; w < 4; ++w) {
      const float qw0 = c4(q0, w), qw1 = c4(q1, w), qw2 = c4(q2, w);
      const float kw0 = c4(k0, w), kw1 = c4(k1, w), kw2 = c4(k2, w);
      s[w][0][0] = fmaf(qw0, kw0, s[w][0][0]);
      s[w][0][1] = fmaf(qw0, kw1, s[w][0][1]);
      s[w][0][2] = fmaf(qw0, kw2, s[w][0][2]);
      s[w][1][0] = fmaf(qw1, kw0, s[w][1][0]);
      s[w][1][1] = fmaf(qw1, kw1, s[w][1][1]);
      s[w][1][2] = fmaf(qw1, kw2, s[w][1][2]);
      s[w][2][0] = fmaf(qw2, kw0, s[w][2][0]);
      s[w][2][1] = fmaf(qw2, kw1, s[w][2][1]);
      s[w][2][2] = fmaf(qw2, kw2, s[w][2][2]);
    }
  }

  // ---- softmax over kj, per (w, kq); p reuses s storage semantics
  const float scale = 0.17677669529663687f;  // 32^-0.5
  float p[4][3][3];
  #pragma unroll
  for (int w = 0; w < 4; ++w) {
    #pragma unroll
    for (int a = 0; a < 3; ++a) {
      const float x0 = s[w][a][0] * scale, x1 = s[w][a][1] * scale, x2 = s[w][a][2] * scale;
      const float m = fmaxf(fmaxf(x0, x1), x2);
      const float e0 = __expf(x0 - m), e1 = __expf(x1 - m), e2 = __expf(x2 - m);
      const float r = 1.f / (e0 + e1 + e2);
      p[w][a][0] = e0 * r; p[w][a][1] = e1 * r; p[w][a][2] = e2 * r;
    }
  }

  // ---- PV, window-outer: per window write a contiguous 384B chunk.
  // v re-read per w; repeats hit L2/L3 (no extra HBM traffic).
  const size_t obbase = (size_t)b * ((size_t)CG * CH * KS * HD) + (size_t)hh * (KS * HD);
  #pragma unroll
  for (int w = 0; w < 4; ++w) {
    float* ob = out + obbase + (size_t)(g4 * 4 + w) * (CH * KS * HD);
    #pragma unroll 2
    for (int dd4 = 0; dd4 < HD / 4; ++dd4) {
      float o[3][4];
      #pragma unroll
      for (int l = 0; l < 4; ++l) {
        const int dd = dd4 * 4 + l;
        const float4 v0 = vb[dd * CN4 + 0 * CG4];
        const float4 v1 = vb[dd * CN4 + 1 * CG4];
        const float4 v2 = vb[dd * CN4 + 2 * CG4];
        const float vw0 = c4(v0, w), vw1 = c4(v1, w), vw2 = c4(v2, w);
        #pragma unroll
        for (int a = 0; a < 3; ++a)
          o[a][l] = fmaf(p[w][a][0], vw0, fmaf(p[w][a][1], vw1, p[w][a][2] * vw2));
      }
      #pragma unroll
      for (int a = 0; a < 3; ++a)
        *reinterpret_cast<float4*>(ob + a * HD + dd4 * 4) =
            make_float4(o[a][0], o[a][1], o[a][2], o[a][3]);
    }
  }
}

extern "C" void kernel_launch(void* const* d_in, const int* in_sizes, int n_in,
                              void* d_out, int out_size, void* d_ws, size_t ws_size,
                              hipStream_t stream) {
  const float* q = (const float*)d_in[0];
  const float* k = (const float*)d_in[1];
  const float* v = (const float*)d_in[2];
  float* out = (float*)d_out;

  const int total = CB * CH * NG4;   // 98304 threads, one per (b,h,window-quad)
  const int blocks = total / 64;     // 1536 blocks x 1 wave = 6 waves/CU, balanced
  dilate_attn_kernel<<<blocks, 64, 0, stream>>>(q, k, v, out);
}

// Round 4
// 173.106 us; speedup vs baseline: 1.6317x; 1.6317x over previous
//
#include <hip/hip_runtime.h>

// q,k,v: [B=8, d=768, N=6144] fp32; head_dim=32, kernel_size=3
// h = 24 heads, g = 2048 windows; window elem j of window gg at n = j*2048 + gg
// out flat: [b][gg][hh][kq][dd] contiguous [8, 2048, 24, 3, 32]
//
// Round-2 structure (1 window/thread, 24 waves/CU, every input read once,
// scalar fully-coalesced reads) + register-buffered PV output flushed in
// back-to-back float4 bursts so each 64B output line is completed within a
// few instructions (kills the 2.1x partial-line write amplification seen in
// round 2 without sacrificing occupancy like round 3 did).
constexpr int CB = 8;
constexpr int CD = 768;
constexpr int CN = 6144;
constexpr int HD = 32;
constexpr int KS = 3;
constexpr int CH = CD / HD;   // 24
constexpr int CG = CN / KS;   // 2048

__global__ __launch_bounds__(256) void dilate_attn_kernel(
    const float* __restrict__ q, const float* __restrict__ k,
    const float* __restrict__ v, float* __restrict__ out) {
  const int idx = blockIdx.x * 256 + threadIdx.x;  // (b, hh, gg), gg fastest
  const int gg = idx & (CG - 1);
  const int bh = idx >> 11;        // b*24 + hh
  const int hh = bh % CH;
  const int b  = bh / CH;

  const size_t inbase = ((size_t)b * CD + (size_t)hh * HD) * (size_t)CN + (size_t)gg;
  const float* qb = q + inbase;
  const float* kb = k + inbase;
  const float* vb = v + inbase;

  // ---- scores: s[kq][kj] = sum_dd q[kq*G+gg + dd*N] * k[kj*G+gg + dd*N]
  float s00 = 0.f, s01 = 0.f, s02 = 0.f;
  float s10 = 0.f, s11 = 0.f, s12 = 0.f;
  float s20 = 0.f, s21 = 0.f, s22 = 0.f;
  #pragma unroll 8
  for (int dd = 0; dd < HD; ++dd) {
    const float* qp = qb + (size_t)dd * CN;
    const float* kp = kb + (size_t)dd * CN;
    const float q0 = qp[0], q1 = qp[CG], q2 = qp[2 * CG];
    const float k0 = kp[0], k1 = kp[CG], k2 = kp[2 * CG];
    s00 = fmaf(q0, k0, s00); s01 = fmaf(q0, k1, s01); s02 = fmaf(q0, k2, s02);
    s10 = fmaf(q1, k0, s10); s11 = fmaf(q1, k1, s11); s12 = fmaf(q1, k2, s12);
    s20 = fmaf(q2, k0, s20); s21 = fmaf(q2, k1, s21); s22 = fmaf(q2, k2, s22);
  }

  const float scale = 0.17677669529663687f;  // 32^-0.5
  s00 *= scale; s01 *= scale; s02 *= scale;
  s10 *= scale; s11 *= scale; s12 *= scale;
  s20 *= scale; s21 *= scale; s22 *= scale;

  // ---- softmax over kj (last axis), per row kq
  const float m0 = fmaxf(fmaxf(s00, s01), s02);
  const float m1 = fmaxf(fmaxf(s10, s11), s12);
  const float m2 = fmaxf(fmaxf(s20, s21), s22);
  const float e00 = __expf(s00 - m0), e01 = __expf(s01 - m0), e02 = __expf(s02 - m0);
  const float e10 = __expf(s10 - m1), e11 = __expf(s11 - m1), e12 = __expf(s12 - m1);
  const float e20 = __expf(s20 - m2), e21 = __expf(s21 - m2), e22 = __expf(s22 - m2);
  const float r0 = 1.f / (e00 + e01 + e02);
  const float r1 = 1.f / (e10 + e11 + e12);
  const float r2 = 1.f / (e20 + e21 + e22);
  const float p00 = e00 * r0, p01 = e01 * r0, p02 = e02 * r0;
  const float p10 = e10 * r1, p11 = e11 * r1, p12 = e12 * r1;
  const float p20 = e20 * r2, p21 = e21 * r2, p22 = e22 * r2;

  // ---- PV into register buffer, flushed in 2 halves of 12 back-to-back
  // float4 stores (3 full aligned 64B lines per burst per thread).
  float* ob = out + ((size_t)b * CG + (size_t)gg) * (size_t)(CH * KS * HD)
                  + (size_t)hh * (KS * HD);
  #pragma unroll
  for (int half = 0; half < 2; ++half) {
    float o0[16], o1[16], o2[16];
    #pragma unroll
    for (int l = 0; l < 16; ++l) {
      const int dd = half * 16 + l;
      const float* vp = vb + (size_t)dd * CN;
      const float v0 = vp[0], v1 = vp[CG], v2 = vp[2 * CG];
      o0[l] = fmaf(p00, v0, fmaf(p01, v1, p02 * v2));
      o1[l] = fmaf(p10, v0, fmaf(p11, v1, p12 * v2));
      o2[l] = fmaf(p20, v0, fmaf(p21, v1, p22 * v2));
    }
    float* obh = ob + half * 16;
    #pragma unroll
    for (int c = 0; c < 4; ++c)
      *reinterpret_cast<float4*>(obh + 0 * HD + c * 4) =
          make_float4(o0[c * 4], o0[c * 4 + 1], o0[c * 4 + 2], o0[c * 4 + 3]);
    #pragma unroll
    for (int c = 0; c < 4; ++c)
      *reinterpret_cast<float4*>(obh + 1 * HD + c * 4) =
          make_float4(o1[c * 4], o1[c * 4 + 1], o1[c * 4 + 2], o1[c * 4 + 3]);
    #pragma unroll
    for (int c = 0; c < 4; ++c)
      *reinterpret_cast<float4*>(obh + 2 * HD + c * 4) =
          make_float4(o2[c * 4], o2[c * 4 + 1], o2[c * 4 + 2], o2[c * 4 + 3]);
  }
}

extern "C" void kernel_launch(void* const* d_in, const int* in_sizes, int n_in,
                              void* d_out, int out_size, void* d_ws, size_t ws_size,
                              hipStream_t stream) {
  const float* q = (const float*)d_in[0];
  const float* k = (const float*)d_in[1];
  const float* v = (const float*)d_in[2];
  float* out = (float*)d_out;

  const int total = CB * CH * CG;            // 393216 threads, one per (b,h,gg)
  const int blocks = total / 256;            // 1536 blocks x 4 waves = 24 waves/CU
  dilate_attn_kernel<<<blocks, 256, 0, stream>>>(q, k, v, out);
}

// Round 5
// 129.061 us; speedup vs baseline: 2.1886x; 1.3413x over previous
//
#include <hip/hip_runtime.h>

// q,k,v: [B=8, d=768, N=6144] fp32; head_dim=32, kernel_size=3
// h = 24 heads, g = 2048 windows; window elem j of window gg at n = j*2048 + gg
// out flat: [b][gg][hh][kq][dd] contiguous [8, 2048, 24, 3, 32]
//
// Round 5: 2 threads per window, split by dd-half (0-15 / 16-31).
//  - scores: each half accumulates partial s[3][3], combined via one
//    __shfl_xor(.,32) per score (lanes 0-31 = half 0, lanes 32-63 = half 1)
//  - softmax recomputed redundantly in both halves (9 values, cheap)
//  - PV + store: each thread handles its own 16 dd -> 3 full 64B lines
//  => 12288 waves (48/CU supplied vs ~16-20 resident): backfill pool smooths
//     the L3-hit/miss tail that capped round 4 at 27% occupancy / 2.15 TB/s.
constexpr int CB = 8;
constexpr int CD = 768;
constexpr int CN = 6144;
constexpr int HD = 32;
constexpr int KS = 3;
constexpr int CH = CD / HD;   // 24
constexpr int CG = CN / KS;   // 2048

__global__ __launch_bounds__(256) void dilate_attn_kernel(
    const float* __restrict__ q, const float* __restrict__ k,
    const float* __restrict__ v, float* __restrict__ out) {
  const int tid  = blockIdx.x * 256 + threadIdx.x;
  const int lane = threadIdx.x & 63;
  const int wav  = tid >> 6;          // global wave id, 0..12287
  const int half = lane >> 5;         // dd-half: 0 -> dd 0-15, 1 -> dd 16-31
  const int wl   = lane & 31;         // window-within-wave
  const int gg   = (wav & 63) * 32 + wl;   // 64 waves cover one (b,hh)'s 2048 windows
  const int bh   = wav >> 6;          // b*24 + hh
  const int hh   = bh % CH;
  const int b    = bh / CH;

  // this thread's 16 rows start at dd = half*16
  const size_t rowbase = ((size_t)b * CD + (size_t)(hh * HD + half * 16)) * (size_t)CN
                       + (size_t)gg;
  const float* qb = q + rowbase;
  const float* kb = k + rowbase;
  const float* vb = v + rowbase;

  // ---- partial scores over this half's 16 dd
  float s00 = 0.f, s01 = 0.f, s02 = 0.f;
  float s10 = 0.f, s11 = 0.f, s12 = 0.f;
  float s20 = 0.f, s21 = 0.f, s22 = 0.f;
  #pragma unroll 8
  for (int d = 0; d < 16; ++d) {
    const float* qp = qb + (size_t)d * CN;
    const float* kp = kb + (size_t)d * CN;
    const float q0 = qp[0], q1 = qp[CG], q2 = qp[2 * CG];
    const float k0 = kp[0], k1 = kp[CG], k2 = kp[2 * CG];
    s00 = fmaf(q0, k0, s00); s01 = fmaf(q0, k1, s01); s02 = fmaf(q0, k2, s02);
    s10 = fmaf(q1, k0, s10); s11 = fmaf(q1, k1, s11); s12 = fmaf(q1, k2, s12);
    s20 = fmaf(q2, k0, s20); s21 = fmaf(q2, k1, s21); s22 = fmaf(q2, k2, s22);
  }

  // ---- combine halves: partner is lane ^ 32
  s00 += __shfl_xor(s00, 32); s01 += __shfl_xor(s01, 32); s02 += __shfl_xor(s02, 32);
  s10 += __shfl_xor(s10, 32); s11 += __shfl_xor(s11, 32); s12 += __shfl_xor(s12, 32);
  s20 += __shfl_xor(s20, 32); s21 += __shfl_xor(s21, 32); s22 += __shfl_xor(s22, 32);

  const float scale = 0.17677669529663687f;  // 32^-0.5
  s00 *= scale; s01 *= scale; s02 *= scale;
  s10 *= scale; s11 *= scale; s12 *= scale;
  s20 *= scale; s21 *= scale; s22 *= scale;

  // ---- softmax over kj, per row kq (redundant in both halves)
  const float m0 = fmaxf(fmaxf(s00, s01), s02);
  const float m1 = fmaxf(fmaxf(s10, s11), s12);
  const float m2 = fmaxf(fmaxf(s20, s21), s22);
  const float e00 = __expf(s00 - m0), e01 = __expf(s01 - m0), e02 = __expf(s02 - m0);
  const float e10 = __expf(s10 - m1), e11 = __expf(s11 - m1), e12 = __expf(s12 - m1);
  const float e20 = __expf(s20 - m2), e21 = __expf(s21 - m2), e22 = __expf(s22 - m2);
  const float r0 = 1.f / (e00 + e01 + e02);
  const float r1 = 1.f / (e10 + e11 + e12);
  const float r2 = 1.f / (e20 + e21 + e22);
  const float p00 = e00 * r0, p01 = e01 * r0, p02 = e02 * r0;
  const float p10 = e10 * r1, p11 = e11 * r1, p12 = e12 * r1;
  const float p20 = e20 * r2, p21 = e21 * r2, p22 = e22 * r2;

  // ---- PV over this half's 16 dd (fully unrolled: o[] stays in registers)
  float o0[16], o1[16], o2[16];
  #pragma unroll
  for (int d = 0; d < 16; ++d) {
    const float* vp = vb + (size_t)d * CN;
    const float v0 = vp[0], v1 = vp[CG], v2 = vp[2 * CG];
    o0[d] = fmaf(p00, v0, fmaf(p01, v1, p02 * v2));
    o1[d] = fmaf(p10, v0, fmaf(p11, v1, p12 * v2));
    o2[d] = fmaf(p20, v0, fmaf(p21, v1, p22 * v2));
  }

  // ---- store: 3 full aligned 64B lines per thread, back-to-back
  float* ob = out + ((size_t)b * CG + (size_t)gg) * (size_t)(CH * KS * HD)
                  + (size_t)hh * (KS * HD) + (size_t)half * 16;
  #pragma unroll
  for (int c = 0; c < 4; ++c)
    *reinterpret_cast<float4*>(ob + 0 * HD + c * 4) =
        make_float4(o0[c * 4], o0[c * 4 + 1], o0[c * 4 + 2], o0[c * 4 + 3]);
  #pragma unroll
  for (int c = 0; c < 4; ++c)
    *reinterpret_cast<float4*>(ob + 1 * HD + c * 4) =
        make_float4(o1[c * 4], o1[c * 4 + 1], o1[c * 4 + 2], o1[c * 4 + 3]);
  #pragma unroll
  for (int c = 0; c < 4; ++c)
    *reinterpret_cast<float4*>(ob + 2 * HD + c * 4) =
        make_float4(o2[c * 4], o2[c * 4 + 1], o2[c * 4 + 2], o2[c * 4 + 3]);
}

extern "C" void kernel_launch(void* const* d_in, const int* in_sizes, int n_in,
                              void* d_out, int out_size, void* d_ws, size_t ws_size,
                              hipStream_t stream) {
  const float* q = (const float*)d_in[0];
  const float* k = (const float*)d_in[1];
  const float* v = (const float*)d_in[2];
  float* out = (float*)d_out;

  const int total = CB * CH * CG * 2;        // 786432 threads, 2 per window
  const int blocks = total / 256;            // 3072 blocks = 12288 waves = 48/CU supplied
  dilate_attn_kernel<<<blocks, 256, 0, stream>>>(q, k, v, out);
}